// Round 1
// baseline (417.472 us; speedup 1.0000x reference)
//
#include <hip/hip_runtime.h>
#include <hip/hip_bf16.h>

#define M_TOTAL 16384   // B*S = 4*4096
#define DIN 512
#define DOUT 64
#define SEQ 4096
#define NSPLIT 8
#define KVSPLIT 512     // SEQ/NSPLIT

// workspace layout (floats)
static constexpr size_t QOFF = 0;
static constexpr size_t KOFF = (size_t)M_TOTAL * DOUT;             // 1 M floats
static constexpr size_t VOFF = 2 * KOFF;
static constexpr size_t OOFF = 3 * KOFF;                           // partial O: NSPLIT * M * 64
static constexpr size_t MOFF = OOFF + (size_t)NSPLIT * M_TOTAL * DOUT;
static constexpr size_t LOFF = MOFF + (size_t)NSPLIT * M_TOTAL;
// total = LOFF + NSPLIT*M_TOTAL = 11,796,480 floats = 45 MiB

__device__ __forceinline__ float quad_sum(float v) {
  // sum across the 4 lanes of a DPP quad (lanes 4k..4k+3) via quad_perm
  int i = __builtin_bit_cast(int, v);
  v += __builtin_bit_cast(float, __builtin_amdgcn_mov_dpp(i, 0xB1, 0xF, 0xF, true)); // xor 1
  i = __builtin_bit_cast(int, v);
  v += __builtin_bit_cast(float, __builtin_amdgcn_mov_dpp(i, 0x4E, 0xF, 0xF, true)); // xor 2
  return v;
}

__device__ __forceinline__ float dot4(const float4& a, const float4& b) {
  return a.x * b.x + a.y * b.y + a.z * b.z + a.w * b.w;
}

// ---------------- QKV projection: [16384,512] x [64,512]^T -> [16384,64] x3 ----------------
// block tile 128 rows x 64 cols, 256 threads, thread tile 8 rows x 4 cols, K chunks of 64.
__global__ __launch_bounds__(256) void proj_kernel(
    const float* __restrict__ x, const float* __restrict__ Wq,
    const float* __restrict__ Wk, const float* __restrict__ Wv,
    float* __restrict__ ws) {
  __shared__ __attribute__((aligned(16))) float xs[128 * 68];
  __shared__ __attribute__((aligned(16))) float wt[64 * 68];  // W^T chunk: wt[k][col]

  const int rb  = blockIdx.x;
  const int mat = blockIdx.y;
  const float* W = (mat == 0) ? Wq : ((mat == 1) ? Wk : Wv);
  float* out = ws + (size_t)mat * KOFF;

  const int tid = threadIdx.x;
  const int ct  = tid & 15;   // col-thread: cols ct*4..+3
  const int rt  = tid >> 4;   // row-thread: rows rt*8..+7

  float4 acc[8];
#pragma unroll
  for (int i = 0; i < 8; i++) acc[i] = make_float4(0.f, 0.f, 0.f, 0.f);

  for (int c = 0; c < 8; c++) {
    const int k0 = c * 64;
    // stage x tile [128][64]
#pragma unroll
    for (int it = 0; it < 8; it++) {
      int fi = tid + it * 256;
      int row = fi >> 4, c4 = fi & 15;
      float4 v = *(const float4*)(x + (size_t)(rb * 128 + row) * DIN + k0 + c4 * 4);
      *(float4*)(xs + row * 68 + c4 * 4) = v;
    }
    // stage W^T chunk [64k][64col]
#pragma unroll
    for (int it = 0; it < 4; it++) {
      int fi = tid + it * 256;
      int col = fi >> 4, k4 = fi & 15;
      float4 w = *(const float4*)(W + (size_t)col * DIN + k0 + k4 * 4);
      wt[(k4 * 4 + 0) * 68 + col] = w.x;
      wt[(k4 * 4 + 1) * 68 + col] = w.y;
      wt[(k4 * 4 + 2) * 68 + col] = w.z;
      wt[(k4 * 4 + 3) * 68 + col] = w.w;
    }
    __syncthreads();
#pragma unroll
    for (int kq = 0; kq < 16; kq++) {
      float4 a[8], b[4];
#pragma unroll
      for (int i = 0; i < 8; i++) a[i] = *(const float4*)(xs + (rt * 8 + i) * 68 + kq * 4);
#pragma unroll
      for (int m = 0; m < 4; m++) b[m] = *(const float4*)(wt + (kq * 4 + m) * 68 + ct * 4);
#pragma unroll
      for (int i = 0; i < 8; i++) {
        const float* ai = &a[i].x;
#pragma unroll
        for (int m = 0; m < 4; m++) {
          float av = ai[m];
          acc[i].x += av * b[m].x;
          acc[i].y += av * b[m].y;
          acc[i].z += av * b[m].z;
          acc[i].w += av * b[m].w;
        }
      }
    }
    __syncthreads();
  }
#pragma unroll
  for (int i = 0; i < 8; i++) {
    int row = rb * 128 + rt * 8 + i;
    *(float4*)(out + (size_t)row * DOUT + ct * 4) = acc[i];
  }
}

// ---------------- flash attention partial (fp32), kv-split across blocks ----------------
// block: 256 threads = 64 quads; quad owns 4 q-rows; lane-in-quad owns 16 of 64 dims.
__global__ __launch_bounds__(256, 2) void attn_kernel(float* __restrict__ ws) {
  __shared__ __attribute__((aligned(16))) float ks[64 * 64];
  __shared__ __attribute__((aligned(16))) float vs[64 * 64];

  const int tid  = threadIdx.x;
  const int qb   = blockIdx.x;   // 0..63 : q-row block of 256
  const int sp   = blockIdx.y;   // 0..NSPLIT-1 : kv split
  const int dgrp = tid & 3;      // dim group: dims dgrp*16..+15
  const int quad = tid >> 2;     // 0..63
  const int row0 = qb * 256 + quad * 4;
  const int batch = qb >> 4;     // 4096/256 = 16 qblocks per batch

  const float* qp = ws + QOFF;
  const float* kp = ws + KOFF + ((size_t)batch * SEQ + (size_t)sp * KVSPLIT) * DOUT;
  const float* vp = ws + VOFF + ((size_t)batch * SEQ + (size_t)sp * KVSPLIT) * DOUT;

  float4 qr[4][4];
#pragma unroll
  for (int r = 0; r < 4; r++)
#pragma unroll
    for (int m = 0; m < 4; m++) {
      float4 t = *(const float4*)(qp + (size_t)(row0 + r) * DOUT + dgrp * 16 + m * 4);
      qr[r][m] = make_float4(t.x * 0.125f, t.y * 0.125f, t.z * 0.125f, t.w * 0.125f);
    }
  float4 o[4][4];
#pragma unroll
  for (int r = 0; r < 4; r++)
#pragma unroll
    for (int m = 0; m < 4; m++) o[r][m] = make_float4(0.f, 0.f, 0.f, 0.f);
  float mrow[4] = {-__builtin_inff(), -__builtin_inff(), -__builtin_inff(), -__builtin_inff()};
  float lrow[4] = {0.f, 0.f, 0.f, 0.f};

  for (int t = 0; t < KVSPLIT / 64; t++) {
    const float4* ksrc = (const float4*)(kp + (size_t)t * 64 * DOUT);
    const float4* vsrc = (const float4*)(vp + (size_t)t * 64 * DOUT);
    float4* kdst = (float4*)ks;
    float4* vdst = (float4*)vs;
#pragma unroll
    for (int it = 0; it < 4; it++) {
      kdst[tid + it * 256] = ksrc[tid + it * 256];
      vdst[tid + it * 256] = vsrc[tid + it * 256];
    }
    __syncthreads();
#pragma unroll 2
    for (int j = 0; j < 64; j++) {
      float4 kk[4], vv[4];
#pragma unroll
      for (int m = 0; m < 4; m++) kk[m] = *(const float4*)(ks + j * 64 + dgrp * 16 + m * 4);
#pragma unroll
      for (int m = 0; m < 4; m++) vv[m] = *(const float4*)(vs + j * 64 + dgrp * 16 + m * 4);
      float s[4];
#pragma unroll
      for (int r = 0; r < 4; r++) {
        float a = dot4(qr[r][0], kk[0]) + dot4(qr[r][1], kk[1]) +
                  dot4(qr[r][2], kk[2]) + dot4(qr[r][3], kk[3]);
        s[r] = quad_sum(a);   // full 64-dim dot, identical in all 4 quad lanes
      }
#pragma unroll
      for (int r = 0; r < 4; r++) {
        if (s[r] > mrow[r]) {            // defer-max: rescale only on new max (~ln(512)/row)
          float corr = __expf(mrow[r] - s[r]);   // exp(-inf)=0 handles init
          mrow[r] = s[r];
          lrow[r] *= corr;
#pragma unroll
          for (int m = 0; m < 4; m++) {
            o[r][m].x *= corr; o[r][m].y *= corr; o[r][m].z *= corr; o[r][m].w *= corr;
          }
        }
        float p = __expf(s[r] - mrow[r]);
        lrow[r] += p;
#pragma unroll
        for (int m = 0; m < 4; m++) {
          o[r][m].x += p * vv[m].x; o[r][m].y += p * vv[m].y;
          o[r][m].z += p * vv[m].z; o[r][m].w += p * vv[m].w;
        }
      }
    }
    __syncthreads();
  }
  // write unnormalized partials + (m,l)
#pragma unroll
  for (int r = 0; r < 4; r++)
#pragma unroll
    for (int m = 0; m < 4; m++)
      *(float4*)(ws + OOFF + ((size_t)sp * M_TOTAL + row0 + r) * DOUT + dgrp * 16 + m * 4) = o[r][m];
  if (dgrp == 0) {
#pragma unroll
    for (int r = 0; r < 4; r++) {
      ws[MOFF + (size_t)sp * M_TOTAL + row0 + r] = mrow[r];
      ws[LOFF + (size_t)sp * M_TOTAL + row0 + r] = lrow[r];
    }
  }
}

// ---------------- merge the NSPLIT partials ----------------
__global__ __launch_bounds__(256) void merge_kernel(const float* __restrict__ ws,
                                                    float* __restrict__ out) {
  int gid  = blockIdx.x * 256 + threadIdx.x;  // 65536 threads
  int row  = gid >> 2;
  int dgrp = gid & 3;
  float mv[NSPLIT];
  float mg = -__builtin_inff();
#pragma unroll
  for (int i = 0; i < NSPLIT; i++) {
    mv[i] = ws[MOFF + (size_t)i * M_TOTAL + row];
    mg = fmaxf(mg, mv[i]);
  }
  float den = 0.f, w[NSPLIT];
#pragma unroll
  for (int i = 0; i < NSPLIT; i++) {
    w[i] = __expf(mv[i] - mg);
    den += w[i] * ws[LOFF + (size_t)i * M_TOTAL + row];
  }
  float4 acc[4];
#pragma unroll
  for (int m = 0; m < 4; m++) acc[m] = make_float4(0.f, 0.f, 0.f, 0.f);
#pragma unroll
  for (int i = 0; i < NSPLIT; i++) {
#pragma unroll
    for (int m = 0; m < 4; m++) {
      float4 t = *(const float4*)(ws + OOFF + ((size_t)i * M_TOTAL + row) * DOUT + dgrp * 16 + m * 4);
      acc[m].x += w[i] * t.x; acc[m].y += w[i] * t.y;
      acc[m].z += w[i] * t.z; acc[m].w += w[i] * t.w;
    }
  }
  float inv = 1.f / den;
#pragma unroll
  for (int m = 0; m < 4; m++) {
    float4 r = make_float4(acc[m].x * inv, acc[m].y * inv, acc[m].z * inv, acc[m].w * inv);
    *(float4*)(out + (size_t)row * DOUT + dgrp * 16 + m * 4) = r;
  }
}

extern "C" void kernel_launch(void* const* d_in, const int* in_sizes, int n_in,
                              void* d_out, int out_size, void* d_ws, size_t ws_size,
                              hipStream_t stream) {
  const float* x  = (const float*)d_in[0];
  const float* Wq = (const float*)d_in[1];
  const float* Wk = (const float*)d_in[2];
  const float* Wv = (const float*)d_in[3];
  float* out = (float*)d_out;
  float* ws  = (float*)d_ws;
  (void)in_sizes; (void)n_in; (void)out_size; (void)ws_size;

  proj_kernel<<<dim3(M_TOTAL / 128, 3), 256, 0, stream>>>(x, Wq, Wk, Wv, ws);
  attn_kernel<<<dim3(M_TOTAL / 256, NSPLIT), 256, 0, stream>>>(ws);
  merge_kernel<<<dim3(M_TOTAL * 4 / 256), 256, 0, stream>>>(ws, out);
}

// Round 2
// 163.053 us; speedup vs baseline: 2.5604x; 2.5604x over previous
//
#include <hip/hip_runtime.h>
#include <hip/hip_bf16.h>

#define M_TOTAL 16384   // B*S
#define DIN 512
#define DOUT 64
#define SEQ 4096
#define NSPLIT 2
#define KVSPLIT 2048    // SEQ/NSPLIT

typedef float f32x4 __attribute__((ext_vector_type(4)));
typedef short bf16x8 __attribute__((ext_vector_type(8)));
typedef unsigned short u16;

// ws byte offsets
static constexpr size_t QF = 0;                 // fp32 Q [M,64]   4MB
static constexpr size_t KF = 4u << 20;          // fp32 K          4MB
static constexpr size_t VF = 8u << 20;          // fp32 V          4MB
static constexpr size_t QHo = 12u << 20;        // bf16 Q_hi (pre-scaled by 0.125*log2e)
static constexpr size_t QLo = 14u << 20;        // bf16 Q_lo
static constexpr size_t KHo = 16u << 20;        // bf16 K_hi
static constexpr size_t KLo = 18u << 20;        // bf16 K_lo
static constexpr size_t VTo = 20u << 20;        // bf16 V^T [B][64][SEQ]  2MB
static constexpr size_t OPo = 22u << 20;        // fp32 partials: 2 x [M,64]  8MB
static constexpr size_t MMo = 30u << 20;        // fp32 m: 2 x [M]
static constexpr size_t LLx = MMo + (128u << 10); // fp32 l: 2 x [M]

__device__ __forceinline__ u16 bf16u(float x) {
  return __builtin_bit_cast(u16, __float2bfloat16(x));
}

// ---------------- QKV projection (fp32, unchanged) ----------------
__global__ __launch_bounds__(256) void proj_kernel(
    const float* __restrict__ x, const float* __restrict__ Wq,
    const float* __restrict__ Wk, const float* __restrict__ Wv,
    float* __restrict__ ws) {
  __shared__ __attribute__((aligned(16))) float xs[128 * 68];
  __shared__ __attribute__((aligned(16))) float wt[64 * 68];

  const int rb  = blockIdx.x;
  const int mat = blockIdx.y;
  const float* W = (mat == 0) ? Wq : ((mat == 1) ? Wk : Wv);
  float* out = ws + (size_t)mat * M_TOTAL * DOUT;

  const int tid = threadIdx.x;
  const int ct  = tid & 15;
  const int rt  = tid >> 4;

  float4 acc[8];
#pragma unroll
  for (int i = 0; i < 8; i++) acc[i] = make_float4(0.f, 0.f, 0.f, 0.f);

  for (int c = 0; c < 8; c++) {
    const int k0 = c * 64;
#pragma unroll
    for (int it = 0; it < 8; it++) {
      int fi = tid + it * 256;
      int row = fi >> 4, c4 = fi & 15;
      float4 v = *(const float4*)(x + (size_t)(rb * 128 + row) * DIN + k0 + c4 * 4);
      *(float4*)(xs + row * 68 + c4 * 4) = v;
    }
#pragma unroll
    for (int it = 0; it < 4; it++) {
      int fi = tid + it * 256;
      int col = fi >> 4, k4 = fi & 15;
      float4 w = *(const float4*)(W + (size_t)col * DIN + k0 + k4 * 4);
      wt[(k4 * 4 + 0) * 68 + col] = w.x;
      wt[(k4 * 4 + 1) * 68 + col] = w.y;
      wt[(k4 * 4 + 2) * 68 + col] = w.z;
      wt[(k4 * 4 + 3) * 68 + col] = w.w;
    }
    __syncthreads();
#pragma unroll
    for (int kq = 0; kq < 16; kq++) {
      float4 a[8], b[4];
#pragma unroll
      for (int i = 0; i < 8; i++) a[i] = *(const float4*)(xs + (rt * 8 + i) * 68 + kq * 4);
#pragma unroll
      for (int m = 0; m < 4; m++) b[m] = *(const float4*)(wt + (kq * 4 + m) * 68 + ct * 4);
#pragma unroll
      for (int i = 0; i < 8; i++) {
        const float* ai = &a[i].x;
#pragma unroll
        for (int m = 0; m < 4; m++) {
          float av = ai[m];
          acc[i].x += av * b[m].x;
          acc[i].y += av * b[m].y;
          acc[i].z += av * b[m].z;
          acc[i].w += av * b[m].w;
        }
      }
    }
    __syncthreads();
  }
#pragma unroll
  for (int i = 0; i < 8; i++) {
    int row = rb * 128 + rt * 8 + i;
    *(float4*)(out + (size_t)row * DOUT + ct * 4) = acc[i];
  }
}

// ---------------- convert: fp32 qkv -> split-bf16 Q/K, bf16 V^T ----------------
// grid 256 blocks x 256 thr; block handles 64 rows.
__global__ __launch_bounds__(256) void convert_kernel(char* wsb) {
  __shared__ float ls[64][68];
  const int tid = threadIdx.x;
  const int m0 = blockIdx.x * 64;
  const int bb = m0 / SEQ;
  const int s0 = m0 % SEQ;
  const float* Qf = (const float*)(wsb + QF);
  const float* Kf = (const float*)(wsb + KF);
  const float* Vf = (const float*)(wsb + VF);
  u16* qh = (u16*)(wsb + QHo); u16* ql = (u16*)(wsb + QLo);
  u16* kh = (u16*)(wsb + KHo); u16* kl = (u16*)(wsb + KLo);
  u16* vt = (u16*)(wsb + VTo);
  const float QS = 0.18033688011112042f;  // 0.125 * log2(e) -> exp2 domain
  const size_t base = (size_t)m0 * DOUT;

#pragma unroll
  for (int i = 0; i < 4; i++) {
    int e4 = tid + i * 256;                   // float4 index, 0..1023
    // Q: scale, split hi/lo
    {
      float4 q4 = *(const float4*)(Qf + base + e4 * 4);
      const float* qp = &q4.x;
      u16 hi[4], lo[4];
#pragma unroll
      for (int c = 0; c < 4; c++) {
        float xv = qp[c] * QS;
        __hip_bfloat16 hb = __float2bfloat16(xv);
        hi[c] = __builtin_bit_cast(u16, hb);
        lo[c] = bf16u(xv - __bfloat162float(hb));
      }
      *(ushort4*)(qh + base + e4 * 4) = make_ushort4(hi[0], hi[1], hi[2], hi[3]);
      *(ushort4*)(ql + base + e4 * 4) = make_ushort4(lo[0], lo[1], lo[2], lo[3]);
    }
    // K: split hi/lo
    {
      float4 k4 = *(const float4*)(Kf + base + e4 * 4);
      const float* kp = &k4.x;
      u16 hi[4], lo[4];
#pragma unroll
      for (int c = 0; c < 4; c++) {
        float xv = kp[c];
        __hip_bfloat16 hb = __float2bfloat16(xv);
        hi[c] = __builtin_bit_cast(u16, hb);
        lo[c] = bf16u(xv - __bfloat162float(hb));
      }
      *(ushort4*)(kh + base + e4 * 4) = make_ushort4(hi[0], hi[1], hi[2], hi[3]);
      *(ushort4*)(kl + base + e4 * 4) = make_ushort4(lo[0], lo[1], lo[2], lo[3]);
    }
    // V: stage fp32 tile for transpose
    {
      float4 v4 = *(const float4*)(Vf + base + e4 * 4);
      *(float4*)(&ls[e4 >> 4][(e4 & 15) * 4]) = v4;
    }
  }
  __syncthreads();
  // transposed bf16 V^T writes: thread t -> d = t/4, 16 seq elems
  const int d = tid >> 2;
  const int sg = (tid & 3) * 16;
  u16 buf[16];
#pragma unroll
  for (int j = 0; j < 16; j++) buf[j] = bf16u(ls[sg + j][d]);
  u16* dst = vt + ((size_t)(bb * 64 + d)) * SEQ + s0 + sg;
#pragma unroll
  for (int j = 0; j < 4; j++)
    *(ushort4*)(dst + j * 4) = make_ushort4(buf[j*4], buf[j*4+1], buf[j*4+2], buf[j*4+3]);
}

// ---------------- MFMA flash attention (split-bf16 QK^T, bf16 PV) ----------------
// 256 thr = 4 waves x 16 q-rows; KV tile 64; grid (256 q-tiles, 2 kv-splits).
__global__ __launch_bounds__(256, 2) void attn_mfma_kernel(char* wsb) {
  __shared__ __attribute__((aligned(16))) u16 khs[64][72];
  __shared__ __attribute__((aligned(16))) u16 kls[64][72];
  __shared__ __attribute__((aligned(16))) u16 vts[64][72];
  __shared__ __attribute__((aligned(16))) u16 pls[4][16][72];

  const int tid  = threadIdx.x;
  const int lane = tid & 63;
  const int w    = tid >> 6;
  const int qt   = blockIdx.x;
  const int sp   = blockIdx.y;
  const int r16  = lane & 15;   // q-row within wave / A-row / B-col
  const int g    = lane >> 4;   // k-chunk group

  const int qrow = qt * 64 + w * 16 + r16;
  const int bb   = qt >> 6;     // batch (64 q-tiles per batch)

  const u16* Qhg = (const u16*)(wsb + QHo);
  const u16* Qlg = (const u16*)(wsb + QLo);
  const u16* Khg = (const u16*)(wsb + KHo);
  const u16* Klg = (const u16*)(wsb + KLo);
  const u16* Vtg = (const u16*)(wsb + VTo);

  // Q fragments (B-operand of swapped QK^T): lane holds Q[qrow][g*8 + ks*32 + j]
  bf16x8 qhf[2], qlf[2];
#pragma unroll
  for (int ks = 0; ks < 2; ks++) {
    qhf[ks] = *(const bf16x8*)(Qhg + (size_t)qrow * DOUT + g * 8 + ks * 32);
    qlf[ks] = *(const bf16x8*)(Qlg + (size_t)qrow * DOUT + g * 8 + ks * 32);
  }

  f32x4 oacc[4];
#pragma unroll
  for (int dt = 0; dt < 4; dt++) oacc[dt] = (f32x4){0.f, 0.f, 0.f, 0.f};
  float m_run = -__builtin_inff(), l_run = 0.f;

  const int kv0 = bb * SEQ + sp * KVSPLIT;   // global K row base

  for (int t = 0; t < KVSPLIT / 64; t++) {
    const int kvr = kv0 + t * 64;
    // ---- stage K_hi, K_lo, V^T tiles (reg-staged, padded LDS) ----
#pragma unroll
    for (int it = 0; it < 2; it++) {
      int G = tid + it * 256;
      int r = G >> 3, c8 = (G & 7) * 8;
      *(bf16x8*)(&khs[r][c8]) = *(const bf16x8*)(Khg + (size_t)(kvr + r) * DOUT + c8);
      *(bf16x8*)(&kls[r][c8]) = *(const bf16x8*)(Klg + (size_t)(kvr + r) * DOUT + c8);
      *(bf16x8*)(&vts[r][c8]) =
          *(const bf16x8*)(Vtg + (size_t)(bb * 64 + r) * SEQ + sp * KVSPLIT + t * 64 + c8);
    }
    __syncthreads();

    // ---- S^T = K * Q^T (3-term split) ----
    f32x4 sac[4];
#pragma unroll
    for (int kt = 0; kt < 4; kt++) sac[kt] = (f32x4){0.f, 0.f, 0.f, 0.f};
#pragma unroll
    for (int ks = 0; ks < 2; ks++) {
      bf16x8 ka[4], kb[4];
#pragma unroll
      for (int kt = 0; kt < 4; kt++) {
        ka[kt] = *(const bf16x8*)(&khs[kt * 16 + r16][g * 8 + ks * 32]);
        kb[kt] = *(const bf16x8*)(&kls[kt * 16 + r16][g * 8 + ks * 32]);
      }
#pragma unroll
      for (int kt = 0; kt < 4; kt++)
        sac[kt] = __builtin_amdgcn_mfma_f32_16x16x32_bf16(ka[kt], qhf[ks], sac[kt], 0, 0, 0);
#pragma unroll
      for (int kt = 0; kt < 4; kt++)
        sac[kt] = __builtin_amdgcn_mfma_f32_16x16x32_bf16(ka[kt], qlf[ks], sac[kt], 0, 0, 0);
#pragma unroll
      for (int kt = 0; kt < 4; kt++)
        sac[kt] = __builtin_amdgcn_mfma_f32_16x16x32_bf16(kb[kt], qhf[ks], sac[kt], 0, 0, 0);
    }

    // ---- online softmax (exp2 domain; lane owns q-row r16, 16 of 64 k) ----
    float mt = -__builtin_inff();
#pragma unroll
    for (int kt = 0; kt < 4; kt++)
#pragma unroll
      for (int rr = 0; rr < 4; rr++) mt = fmaxf(mt, sac[kt][rr]);
    mt = fmaxf(mt, __shfl_xor(mt, 16));
    mt = fmaxf(mt, __shfl_xor(mt, 32));
    float nm   = fmaxf(m_run, mt);
    float corr = exp2f(m_run - nm);
    float p[16];
    float ts = 0.f;
#pragma unroll
    for (int kt = 0; kt < 4; kt++)
#pragma unroll
      for (int rr = 0; rr < 4; rr++) {
        float pv = exp2f(sac[kt][rr] - nm);
        p[kt * 4 + rr] = pv;
        ts += pv;
      }
    ts += __shfl_xor(ts, 16);
    ts += __shfl_xor(ts, 32);
    l_run = l_run * corr + ts;
    m_run = nm;
#pragma unroll
    for (int dt = 0; dt < 4; dt++) {
      oacc[dt][0] *= corr; oacc[dt][1] *= corr;
      oacc[dt][2] *= corr; oacc[dt][3] *= corr;
    }

    // ---- P -> bf16 LDS (lane's 4 regs are consecutive k) ----
#pragma unroll
    for (int kt = 0; kt < 4; kt++) {
      ushort4 pk = make_ushort4(bf16u(p[kt * 4 + 0]), bf16u(p[kt * 4 + 1]),
                                bf16u(p[kt * 4 + 2]), bf16u(p[kt * 4 + 3]));
      *(ushort4*)(&pls[w][r16][kt * 16 + g * 4]) = pk;
    }

    // ---- O^T += V^T * P^T ----
#pragma unroll
    for (int ks = 0; ks < 2; ks++) {
      bf16x8 pf = *(const bf16x8*)(&pls[w][r16][ks * 32 + g * 8]);
      bf16x8 vf[4];
#pragma unroll
      for (int dt = 0; dt < 4; dt++)
        vf[dt] = *(const bf16x8*)(&vts[dt * 16 + r16][ks * 32 + g * 8]);
#pragma unroll
      for (int dt = 0; dt < 4; dt++)
        oacc[dt] = __builtin_amdgcn_mfma_f32_16x16x32_bf16(vf[dt], pf, oacc[dt], 0, 0, 0);
    }
    __syncthreads();
  }

  // ---- store unnormalized partial O + (m,l) ----
  float* Op = (float*)(wsb + OPo) + (size_t)sp * M_TOTAL * DOUT;
#pragma unroll
  for (int dt = 0; dt < 4; dt++) {
    float4 o4 = make_float4(oacc[dt][0], oacc[dt][1], oacc[dt][2], oacc[dt][3]);
    *(float4*)(Op + (size_t)qrow * DOUT + dt * 16 + g * 4) = o4;
  }
  if (g == 0) {
    ((float*)(wsb + MMo))[(size_t)sp * M_TOTAL + qrow] = m_run;
    ((float*)(wsb + LLx))[(size_t)sp * M_TOTAL + qrow] = l_run;
  }
}

// ---------------- merge 2 kv-splits ----------------
__global__ __launch_bounds__(256) void merge_kernel(const char* __restrict__ wsb,
                                                    float* __restrict__ out) {
  int gid = blockIdx.x * 256 + threadIdx.x;   // 65536 threads
  int row = gid >> 2, dg = gid & 3;
  const float* mp = (const float*)(wsb + MMo);
  const float* lp = (const float*)(wsb + LLx);
  float m0 = mp[row], m1 = mp[M_TOTAL + row];
  float mg = fmaxf(m0, m1);
  float w0 = exp2f(m0 - mg), w1 = exp2f(m1 - mg);
  float den = w0 * lp[row] + w1 * lp[M_TOTAL + row];
  float inv = 1.f / den;
  const float* o0 = (const float*)(wsb + OPo);
  const float* o1 = o0 + (size_t)M_TOTAL * DOUT;
#pragma unroll
  for (int m = 0; m < 4; m++) {
    size_t off = (size_t)row * DOUT + dg * 16 + m * 4;
    float4 a = *(const float4*)(o0 + off);
    float4 b = *(const float4*)(o1 + off);
    float4 r = make_float4((w0 * a.x + w1 * b.x) * inv, (w0 * a.y + w1 * b.y) * inv,
                           (w0 * a.z + w1 * b.z) * inv, (w0 * a.w + w1 * b.w) * inv);
    *(float4*)(out + off) = r;
  }
}

extern "C" void kernel_launch(void* const* d_in, const int* in_sizes, int n_in,
                              void* d_out, int out_size, void* d_ws, size_t ws_size,
                              hipStream_t stream) {
  const float* x  = (const float*)d_in[0];
  const float* Wq = (const float*)d_in[1];
  const float* Wk = (const float*)d_in[2];
  const float* Wv = (const float*)d_in[3];
  float* out = (float*)d_out;
  char* wsb  = (char*)d_ws;
  (void)in_sizes; (void)n_in; (void)out_size; (void)ws_size;

  proj_kernel<<<dim3(M_TOTAL / 128, 3), 256, 0, stream>>>(x, Wq, Wk, Wv, (float*)wsb);
  convert_kernel<<<dim3(M_TOTAL / 64), 256, 0, stream>>>(wsb);
  attn_mfma_kernel<<<dim3(M_TOTAL / 64, NSPLIT), 256, 0, stream>>>(wsb);
  merge_kernel<<<dim3(M_TOTAL * 4 / 256), 256, 0, stream>>>(wsb, out);
}